// Round 3
// baseline (13730.855 us; speedup 1.0000x reference)
//
#include <hip/hip_runtime.h>

#define BB 64
#define HH 512
#define WW 512
#define PLANE (HH * WW)
#define PWR_ITERS 20
#define N_CHEBY 15

// ---------------------------------------------------------------------------
// Power-iteration conv pass:
//   s = conv3x3(in, k[b]) * (1/m_prev[b])   (m_prev==null on first iter)
//   if (write_out) out = s
//   atomicMax(m_out[b], |s|)  (uint-bits trick, values >= 0)
// ---------------------------------------------------------------------------
__global__ __launch_bounds__(256) void conv_pow_kernel(
    const float* __restrict__ in, const float* __restrict__ kern,
    const float* __restrict__ m_prev, float* __restrict__ out,
    unsigned int* __restrict__ m_out, int write_out)
{
    const int b = blockIdx.z;
    const int y = blockIdx.y;
    const int x = blockIdx.x * blockDim.x + threadIdx.x;
    const float* ip = in + (size_t)b * PLANE;

    float k[9];
#pragma unroll
    for (int i = 0; i < 9; ++i) k[i] = kern[b * 9 + i];

    float s = 0.f;
#pragma unroll
    for (int dy = -1; dy <= 1; ++dy) {
        int yy = y + dy;
        if ((unsigned)yy < HH) {
            const float* rp = ip + yy * WW;
#pragma unroll
            for (int dx = -1; dx <= 1; ++dx) {
                int xx = x + dx;
                if ((unsigned)xx < WW) s = fmaf(rp[xx], k[(dy + 1) * 3 + (dx + 1)], s);
            }
        }
    }
    if (m_prev) s *= (1.0f / m_prev[b]);
    if (write_out) out[(size_t)b * PLANE + y * WW + x] = s;

    // block max-|s| reduction: wave shuffle -> LDS -> one atomic per block
    float a = fabsf(s);
#pragma unroll
    for (int o = 32; o; o >>= 1) a = fmaxf(a, __shfl_xor(a, o, 64));
    __shared__ float smax[4];
    int wid = threadIdx.x >> 6;
    if ((threadIdx.x & 63) == 0) smax[wid] = a;
    __syncthreads();
    if (threadIdx.x == 0) {
        float m = smax[0];
        int nw = (int)(blockDim.x >> 6);
        for (int i = 1; i < nw; ++i) m = fmaxf(m, smax[i]);
        atomicMax(m_out + b, __float_as_uint(m));
    }
}

// ---------------------------------------------------------------------------
// taus[it*B + b] = 2 / (m + m/3 - (m/3 - m) * cos(pi*(2*it+1)/30))
// ---------------------------------------------------------------------------
__global__ void tau_kernel(const float* __restrict__ m_final, float* __restrict__ taus)
{
    int i = blockIdx.x * blockDim.x + threadIdx.x;
    if (i >= N_CHEBY * BB) return;
    int it = i / BB;
    int b  = i % BB;
    float m = m_final[b];
    double r = cos(M_PI * (2.0 * it + 1.0) / (2.0 * N_CHEBY));
    float denom = m + m / 3.0f - (m / 3.0f - m) * (float)r;
    taus[i] = 2.0f / denom;
}

// ---------------------------------------------------------------------------
// Chebyshev step: xout = xin + tau[b] * (f - conv3x3(xin, k[b]))
// ---------------------------------------------------------------------------
__global__ __launch_bounds__(256) void cheby_kernel(
    const float* __restrict__ xin, const float* __restrict__ f,
    const float* __restrict__ kern, const float* __restrict__ taus,
    float* __restrict__ xout)
{
    const int b = blockIdx.z;
    const int y = blockIdx.y;
    const int x = blockIdx.x * blockDim.x + threadIdx.x;
    const float* ip = xin + (size_t)b * PLANE;

    float k[9];
#pragma unroll
    for (int i = 0; i < 9; ++i) k[i] = kern[b * 9 + i];

    float s = 0.f;
#pragma unroll
    for (int dy = -1; dy <= 1; ++dy) {
        int yy = y + dy;
        if ((unsigned)yy < HH) {
            const float* rp = ip + yy * WW;
#pragma unroll
            for (int dx = -1; dx <= 1; ++dx) {
                int xx = x + dx;
                if ((unsigned)xx < WW) s = fmaf(rp[xx], k[(dy + 1) * 3 + (dx + 1)], s);
            }
        }
    }
    size_t idx = (size_t)b * PLANE + y * WW + x;
    xout[idx] = ip[y * WW + x] + taus[b] * (f[idx] - s);
}

extern "C" void kernel_launch(void* const* d_in, const int* in_sizes, int n_in,
                              void* d_out, int out_size, void* d_ws, size_t ws_size,
                              hipStream_t stream)
{
    const float* x_in = (const float*)d_in[0];
    const float* f_in = (const float*)d_in[1];
    const float* k_in = (const float*)d_in[2];
    const float* u_in = (const float*)d_in[3];
    float* out = (float*)d_out;

    char* ws = (char*)d_ws;
    float* bufA = (float*)ws;                                        // 64 MB field
    unsigned int* mslots = (unsigned int*)(ws + (size_t)BB * PLANE * 4); // 20*64 uints
    float* taus = (float*)(mslots + PWR_ITERS * BB);                 // 15*64 floats

    // m accumulators must start at 0 every call (ws is poisoned once, and
    // atomicMax accumulation requires a clean slate for determinism).
    hipMemsetAsync(mslots, 0, PWR_ITERS * BB * sizeof(unsigned int), stream);

    dim3 block(256);
    dim3 grid(WW / 256, HH, BB);

    // ---- power iteration: 20 conv passes, normalization folded into reads ----
    const float* src = u_in;
    for (int it = 0; it < PWR_ITERS; ++it) {
        float* dst = (it & 1) ? out : bufA;
        const float* mp = it ? (const float*)(mslots + (size_t)(it - 1) * BB) : nullptr;
        int wr = (it != PWR_ITERS - 1);   // last pass only needs the max
        conv_pow_kernel<<<grid, block, 0, stream>>>(src, k_in, mp, dst,
                                                    mslots + (size_t)it * BB, wr);
        src = dst;
    }

    // ---- tau table ----
    tau_kernel<<<(N_CHEBY * BB + 255) / 256, 256, 0, stream>>>(
        (const float*)(mslots + (size_t)(PWR_ITERS - 1) * BB), taus);

    // ---- 15 Chebyshev steps, ping-pong so iter 14 lands in d_out ----
    const float* xs = x_in;
    for (int it = 0; it < N_CHEBY; ++it) {
        float* dst = (it & 1) ? bufA : out;
        cheby_kernel<<<grid, block, 0, stream>>>(xs, f_in, k_in, taus + (size_t)it * BB, dst);
        xs = dst;
    }
}

// Round 4
// 1390.511 us; speedup vs baseline: 9.8747x; 9.8747x over previous
//
#include <hip/hip_runtime.h>

#define BB 64
#define HH 512
#define WW 512
#define PLANE (HH * WW)
#define PWR_ITERS 20
#define N_CHEBY 15
#define RPB 2              // rows per block
#define GY (HH / RPB)      // 256 blocks in y == blockDim.x

// accumulate one stencil row into 4 outputs (cols c4..c4+3)
__device__ __forceinline__ void row_acc(const float* __restrict__ rp, int c4,
                                        float k0, float k1, float k2,
                                        float& a0, float& a1, float& a2, float& a3)
{
    const float4 cv = *reinterpret_cast<const float4*>(rp + c4);
    const float lf = (c4 > 0)      ? rp[c4 - 1] : 0.f;
    const float rt = (c4 + 4 < WW) ? rp[c4 + 4] : 0.f;
    a0 = fmaf(k0, lf,   fmaf(k1, cv.x, fmaf(k2, cv.y, a0)));
    a1 = fmaf(k0, cv.x, fmaf(k1, cv.y, fmaf(k2, cv.z, a1)));
    a2 = fmaf(k0, cv.y, fmaf(k1, cv.z, fmaf(k2, cv.w, a2)));
    a3 = fmaf(k0, cv.z, fmaf(k1, cv.w, fmaf(k2, rt,   a3)));
}

// ---------------------------------------------------------------------------
// Power-iteration conv pass, NO atomics:
//  1. (it>0) block-reduce prev iter's 256 per-block maxima -> inv = 1/m_prev
//  2. s = conv3x3(in,k[b]) * inv ; optional float4 store
//  3. block max|s| -> pmax_out[b*GY + blockIdx.y]
// ---------------------------------------------------------------------------
__global__ __launch_bounds__(256) void conv_pow_v2(
    const float* __restrict__ in, const float* __restrict__ kern,
    const float* __restrict__ pmax_prev, float* __restrict__ out,
    float* __restrict__ pmax_out)
{
    const int b = blockIdx.z;
    const int t = threadIdx.x;
    __shared__ float sred[4];

    float inv = 1.f;
    if (pmax_prev) {
        float v = pmax_prev[b * GY + t];
#pragma unroll
        for (int o = 32; o; o >>= 1) v = fmaxf(v, __shfl_xor(v, o, 64));
        if ((t & 63) == 0) sred[t >> 6] = v;
        __syncthreads();
        inv = 1.f / fmaxf(fmaxf(sred[0], sred[1]), fmaxf(sred[2], sred[3]));
        __syncthreads();   // protect sred before reuse below
    }

    const float* kb = kern + b * 9;
    const float k00 = kb[0], k01 = kb[1], k02 = kb[2];
    const float k10 = kb[3], k11 = kb[4], k12 = kb[5];
    const float k20 = kb[6], k21 = kb[7], k22 = kb[8];

    const int r  = t >> 7;             // 0..1 row within block
    const int c4 = (t & 127) << 2;     // 0,4,...,508
    const int y  = blockIdx.y * RPB + r;
    const float* ip = in + (size_t)b * PLANE;

    float a0 = 0.f, a1 = 0.f, a2 = 0.f, a3 = 0.f;
    if (y > 0)      row_acc(ip + (size_t)(y - 1) * WW, c4, k00, k01, k02, a0, a1, a2, a3);
                    row_acc(ip + (size_t)y       * WW, c4, k10, k11, k12, a0, a1, a2, a3);
    if (y < HH - 1) row_acc(ip + (size_t)(y + 1) * WW, c4, k20, k21, k22, a0, a1, a2, a3);

    a0 *= inv; a1 *= inv; a2 *= inv; a3 *= inv;

    if (out)
        *reinterpret_cast<float4*>(out + (size_t)b * PLANE + (size_t)y * WW + c4) =
            make_float4(a0, a1, a2, a3);

    float am = fmaxf(fmaxf(fabsf(a0), fabsf(a1)), fmaxf(fabsf(a2), fabsf(a3)));
#pragma unroll
    for (int o = 32; o; o >>= 1) am = fmaxf(am, __shfl_xor(am, o, 64));
    if ((t & 63) == 0) sred[t >> 6] = am;
    __syncthreads();
    if (t == 0)
        pmax_out[b * GY + blockIdx.y] =
            fmaxf(fmaxf(sred[0], sred[1]), fmaxf(sred[2], sred[3]));
}

// ---------------------------------------------------------------------------
// Final reduce of pmax + tau table. One block per b.
// taus[it*BB+b] = 2 / (m + m/3 - (m/3 - m) * cos(pi*(2it+1)/30))
// ---------------------------------------------------------------------------
__global__ __launch_bounds__(256) void tau_v2(const float* __restrict__ pmax_final,
                                              float* __restrict__ taus)
{
    const int b = blockIdx.x;
    const int t = threadIdx.x;
    __shared__ float sred[4];
    float v = pmax_final[b * GY + t];
#pragma unroll
    for (int o = 32; o; o >>= 1) v = fmaxf(v, __shfl_xor(v, o, 64));
    if ((t & 63) == 0) sred[t >> 6] = v;
    __syncthreads();
    const float m = fmaxf(fmaxf(sred[0], sred[1]), fmaxf(sred[2], sred[3]));
    if (t < N_CHEBY) {
        double rr = cos(M_PI * (2.0 * t + 1.0) / (2.0 * N_CHEBY));
        float denom = m + m / 3.0f - (m / 3.0f - m) * (float)rr;
        taus[t * BB + b] = 2.f / denom;
    }
}

// ---------------------------------------------------------------------------
// Chebyshev step: xout = xin + tau[b] * (f - conv3x3(xin,k[b])), float4-wide
// ---------------------------------------------------------------------------
__global__ __launch_bounds__(256) void cheby_v2(
    const float* __restrict__ xin, const float* __restrict__ f,
    const float* __restrict__ kern, const float* __restrict__ taus,
    float* __restrict__ xout)
{
    const int b = blockIdx.z;
    const int t = threadIdx.x;
    const float tau = taus[b];

    const float* kb = kern + b * 9;
    const float k00 = kb[0], k01 = kb[1], k02 = kb[2];
    const float k10 = kb[3], k11 = kb[4], k12 = kb[5];
    const float k20 = kb[6], k21 = kb[7], k22 = kb[8];

    const int r  = t >> 7;
    const int c4 = (t & 127) << 2;
    const int y  = blockIdx.y * RPB + r;
    const float* ip = xin + (size_t)b * PLANE;

    float a0 = 0.f, a1 = 0.f, a2 = 0.f, a3 = 0.f;
    if (y > 0)      row_acc(ip + (size_t)(y - 1) * WW, c4, k00, k01, k02, a0, a1, a2, a3);
    const float* rp = ip + (size_t)y * WW;
    const float4 cx = *reinterpret_cast<const float4*>(rp + c4);
                    row_acc(rp, c4, k10, k11, k12, a0, a1, a2, a3);
    if (y < HH - 1) row_acc(ip + (size_t)(y + 1) * WW, c4, k20, k21, k22, a0, a1, a2, a3);

    const size_t idx = (size_t)b * PLANE + (size_t)y * WW + c4;
    const float4 fv = *reinterpret_cast<const float4*>(f + idx);
    float4 o;
    o.x = fmaf(tau, fv.x - a0, cx.x);
    o.y = fmaf(tau, fv.y - a1, cx.y);
    o.z = fmaf(tau, fv.z - a2, cx.z);
    o.w = fmaf(tau, fv.w - a3, cx.w);
    *reinterpret_cast<float4*>(xout + idx) = o;
}

extern "C" void kernel_launch(void* const* d_in, const int* in_sizes, int n_in,
                              void* d_out, int out_size, void* d_ws, size_t ws_size,
                              hipStream_t stream)
{
    const float* x_in = (const float*)d_in[0];
    const float* f_in = (const float*)d_in[1];
    const float* k_in = (const float*)d_in[2];
    const float* u_in = (const float*)d_in[3];
    float* out = (float*)d_out;

    char* ws = (char*)d_ws;
    float* bufA  = (float*)ws;                                   // 67.1 MB field
    float* pmaxA = (float*)(ws + (size_t)BB * PLANE * 4);        // 64*256 floats
    float* pmaxB = pmaxA + BB * GY;
    float* taus  = pmaxB + BB * GY;

    dim3 blk(256), grd(1, GY, BB);

    // ---- power iteration: 20 conv passes, no atomics, no memsets ----
    const float* src = u_in;
    for (int it = 0; it < PWR_ITERS; ++it) {
        float* dst = (it == PWR_ITERS - 1) ? nullptr : ((it & 1) ? out : bufA);
        const float* pp = it ? ((it & 1) ? pmaxA : pmaxB) : nullptr; // written by it-1
        float* po = (it & 1) ? pmaxB : pmaxA;
        conv_pow_v2<<<grd, blk, 0, stream>>>(src, k_in, pp, dst, po);
        if (dst) src = dst;
    }

    // it=19 wrote pmaxB
    tau_v2<<<BB, 256, 0, stream>>>(pmaxB, taus);

    // ---- 15 Chebyshev steps; iter 14 (even) lands in d_out ----
    const float* xs = x_in;
    for (int it = 0; it < N_CHEBY; ++it) {
        float* dst = (it & 1) ? bufA : out;
        cheby_v2<<<grd, blk, 0, stream>>>(xs, f_in, k_in, taus + (size_t)it * BB, dst);
        xs = dst;
    }
}

// Round 5
// 578.920 us; speedup vs baseline: 23.7181x; 2.4019x over previous
//
#include <hip/hip_runtime.h>

#define BB 64
#define HH 512
#define WW 512
#define PLANE (HH * WW)
#define R 32                  // output rows per stripe
#define NSTRIPE (HH / R)      // 16
#define N_CHEBY 15

// Slice: cols c2-1 .. c2+2 of one row (everything a thread needs for 2 outputs)
struct Sl { float a, b, c, d; };

__device__ __forceinline__ void racc(const Sl& s, float k0, float k1, float k2,
                                     float& o0, float& o1) {
    o0 = fmaf(k0, s.a, fmaf(k1, s.b, fmaf(k2, s.c, o0)));
    o1 = fmaf(k0, s.b, fmaf(k1, s.c, fmaf(k2, s.d, o1)));
}

__device__ __forceinline__ Sl ldsl(const float* pl, int row, int c2, bool ok) {
    Sl s = {0.f, 0.f, 0.f, 0.f};
    if (ok) {
        const float* rp = pl + (size_t)row * WW;
        float2 v = *reinterpret_cast<const float2*>(rp + c2);
        s.b = v.x; s.c = v.y;
        if (c2 > 0)      s.a = rp[c2 - 1];
        if (c2 + 2 < WW) s.d = rp[c2 + 2];
    }
    return s;
}

// ---------------------------------------------------------------------------
// Fused 2-level power pass: z = inv*A(u), w = A(z). Tracks max|z|, max|w|.
// Row pipeline: at step p, load u row yu=ytop-2+p; compute z row yu-1;
// complete z slice (row yu-2) from LDS ring; compute w row yu-3.
// ---------------------------------------------------------------------------
__global__ __launch_bounds__(256) void conv_fused(
    const float* __restrict__ in, const float* __restrict__ kern,
    const float* __restrict__ pm_prev,  // prev pass output maxima [BB*NSTRIPE] or null
    float* __restrict__ out,            // null on last pass
    float* __restrict__ pmw, float* __restrict__ pmz)
{
    const int b = blockIdx.y, stripe = blockIdx.x;
    const int ytop = stripe * R;
    const int t = threadIdx.x, c2 = t << 1;

    __shared__ float ring[2][520];
    __shared__ float sred[8];
    __shared__ float sinv;

    float inv = 1.f;
    if (pm_prev) {
        if (t < 64) {
            float v = (t < NSTRIPE) ? pm_prev[b * NSTRIPE + t] : 0.f;
#pragma unroll
            for (int o = 8; o; o >>= 1) v = fmaxf(v, __shfl_xor(v, o, 64));
            if (t == 0) sinv = 1.f / v;
        }
        __syncthreads();
        inv = sinv;
    }

    const float* kb = kern + b * 9;
    const float k00=kb[0],k01=kb[1],k02=kb[2],k10=kb[3],k11=kb[4],k12=kb[5],
                k20=kb[6],k21=kb[7],k22=kb[8];
    const float* ip = in + (size_t)b * PLANE;
    float* op = out ? out + (size_t)b * PLANE : nullptr;

    Sl u2={0,0,0,0}, u1={0,0,0,0};
    Sl z3={0,0,0,0}, z2={0,0,0,0};
    float zown0 = 0.f, zown1 = 0.f;
    float mz = 0.f, mw = 0.f;

    Sl u0 = ldsl(ip, ytop - 2, c2, (unsigned)(ytop - 2) < HH);  // prefetch p=0 row

    const int STEPS = R + 5;
#pragma unroll 2
    for (int p = 0; p < STEPS; ++p) {
        const int yu = ytop - 2 + p;
        Sl un = ldsl(ip, yu + 1, c2, ((unsigned)(yu + 1) < HH) && (p < R + 3));

        const int rpar = (p + 1) & 1, wpar = p & 1;
        const float znl = ring[rpar][1 + c2];
        const float znr = ring[rpar][4 + c2];
        __syncthreads();
        Sl z1; z1.a = znl; z1.b = zown0; z1.c = zown1; z1.d = znr;  // z row yu-2

        // z row yz = yu-1 from u rows yu-2..yu
        const int yz = yu - 1;
        float zo0 = 0.f, zo1 = 0.f;
        racc(u2, k00,k01,k02, zo0,zo1);
        racc(u1, k10,k11,k12, zo0,zo1);
        racc(u0, k20,k21,k22, zo0,zo1);
        const bool zact = (yz >= ytop - 1) && (yz <= ytop + R) && ((unsigned)yz < HH);
        zo0 = zact ? zo0 * inv : 0.f;
        zo1 = zact ? zo1 * inv : 0.f;
        mz = fmaxf(mz, fmaxf(fabsf(zo0), fabsf(zo1)));

        // w row yw = yu-3 from z rows yu-4..yu-2
        float wo0 = 0.f, wo1 = 0.f;
        racc(z3, k00,k01,k02, wo0,wo1);
        racc(z2, k10,k11,k12, wo0,wo1);
        racc(z1, k20,k21,k22, wo0,wo1);
        const int yw = yu - 3;
        if (yw >= ytop && yw < ytop + R) {
            mw = fmaxf(mw, fmaxf(fabsf(wo0), fabsf(wo1)));
            if (op) *reinterpret_cast<float2*>(op + (size_t)yw * WW + c2) =
                        make_float2(wo0, wo1);
        }

        *reinterpret_cast<float2*>(&ring[wpar][2 + c2]) = make_float2(zo0, zo1);
        if (t == 0)   ring[wpar][1]   = 0.f;
        if (t == 255) ring[wpar][514] = 0.f;
        __syncthreads();

        u2 = u1; u1 = u0; u0 = un;
        z3 = z2; z2 = z1; zown0 = zo0; zown1 = zo1;
    }

#pragma unroll
    for (int o = 32; o; o >>= 1) {
        mz = fmaxf(mz, __shfl_xor(mz, o, 64));
        mw = fmaxf(mw, __shfl_xor(mw, o, 64));
    }
    const int wid = t >> 6;
    if ((t & 63) == 0) { sred[wid] = mz; sred[4 + wid] = mw; }
    __syncthreads();
    if (t == 0) {
        pmz[b * NSTRIPE + stripe] =
            fmaxf(fmaxf(sred[0], sred[1]), fmaxf(sred[2], sred[3]));
        pmw[b * NSTRIPE + stripe] =
            fmaxf(fmaxf(sred[4], sred[5]), fmaxf(sred[6], sred[7]));
    }
}

// ---------------------------------------------------------------------------
// m = max|w|/max|z| from last power pass; taus[l*BB+b].
// ---------------------------------------------------------------------------
__global__ __launch_bounds__(64) void tau_fused(
    const float* __restrict__ pmz, const float* __restrict__ pmw,
    float* __restrict__ taus)
{
    const int b = blockIdx.x, t = threadIdx.x;
    float vz = (t < NSTRIPE) ? pmz[b * NSTRIPE + t] : 0.f;
    float vw = (t < NSTRIPE) ? pmw[b * NSTRIPE + t] : 0.f;
#pragma unroll
    for (int o = 8; o; o >>= 1) {
        vz = fmaxf(vz, __shfl_xor(vz, o, 64));
        vw = fmaxf(vw, __shfl_xor(vw, o, 64));
    }
    if (t < N_CHEBY) {
        const float m = vw / vz;
        const double rr = cos(M_PI * (2.0 * t + 1.0) / (2.0 * N_CHEBY));
        const float denom = m + m / 3.0f - (m / 3.0f - m) * (float)rr;
        taus[t * BB + b] = 2.0f / denom;
    }
}

// ---------------------------------------------------------------------------
// Fused 3-level Chebyshev pass: x_{l+1} = x_l + tau_l*(f - A x_l), l=0..2.
// Levels lag: x1 row = yu-1, x2 = yu-3, x3 = yu-5. f kept in register ring.
// ---------------------------------------------------------------------------
__global__ __launch_bounds__(256) void cheby_fused(
    const float* __restrict__ xin, const float* __restrict__ fin,
    const float* __restrict__ kern, const float* __restrict__ tau3,
    float* __restrict__ xout)
{
    const int b = blockIdx.y, stripe = blockIdx.x;
    const int ytop = stripe * R;
    const int t = threadIdx.x, c2 = t << 1;

    __shared__ float r1[2][520], r2[2][520];

    const float* kb = kern + b * 9;
    const float k00=kb[0],k01=kb[1],k02=kb[2],k10=kb[3],k11=kb[4],k12=kb[5],
                k20=kb[6],k21=kb[7],k22=kb[8];
    const float tau0 = tau3[b], tau1 = tau3[BB + b], tau2 = tau3[2 * BB + b];
    const float* xp = xin + (size_t)b * PLANE;
    const float* fp = fin + (size_t)b * PLANE;
    float* op = xout + (size_t)b * PLANE;

    Sl u2={0,0,0,0}, u1={0,0,0,0};
    Sl a3={0,0,0,0}, a2={0,0,0,0}; float aown0=0.f, aown1=0.f;
    Sl b3={0,0,0,0}, b2={0,0,0,0}; float bown0=0.f, bown1=0.f;
    float2 fh0, fh1, fh2, fh3, fh4;
    fh1 = fh2 = fh3 = fh4 = make_float2(0.f, 0.f);

    Sl u0 = ldsl(xp, ytop - 3, c2, (unsigned)(ytop - 3) < HH);  // prefetch p=0
    {
        const int yf = ytop - 4;
        fh0 = ((unsigned)yf < HH)
            ? *reinterpret_cast<const float2*>(fp + (size_t)yf * WW + c2)
            : make_float2(0.f, 0.f);
    }

    const int STEPS = R + 8;
#pragma unroll 2
    for (int p = 0; p < STEPS; ++p) {
        const int yu = ytop - 3 + p;
        Sl un = ldsl(xp, yu + 1, c2, ((unsigned)(yu + 1) < HH) && (p < R + 5));
        float2 fn = (((unsigned)yu < HH) && (p < R + 5))
            ? *reinterpret_cast<const float2*>(fp + (size_t)yu * WW + c2)
            : make_float2(0.f, 0.f);

        const int rpar = (p + 1) & 1, wpar = p & 1;
        const float anl = r1[rpar][1 + c2], anr = r1[rpar][4 + c2];
        const float bnl = r2[rpar][1 + c2], bnr = r2[rpar][4 + c2];
        __syncthreads();
        Sl a1; a1.a = anl; a1.b = aown0; a1.c = aown1; a1.d = anr;  // x1 row yu-2
        Sl b1; b1.a = bnl; b1.b = bown0; b1.c = bown1; b1.d = bnr;  // x2 row yu-4

        // x1 row y1 = yu-1  (uses f row yu-1 = fh0)
        float s0 = 0.f, s1 = 0.f;
        racc(u2, k00,k01,k02, s0,s1);
        racc(u1, k10,k11,k12, s0,s1);
        racc(u0, k20,k21,k22, s0,s1);
        const int y1 = yu - 1;
        const bool act1 = (y1 >= ytop - 2) && (y1 <= ytop + R + 1) && ((unsigned)y1 < HH);
        const float an0 = act1 ? fmaf(tau0, fh0.x - s0, u1.b) : 0.f;
        const float an1 = act1 ? fmaf(tau0, fh0.y - s1, u1.c) : 0.f;

        // x2 row y2 = yu-3  (uses f row yu-3 = fh2)
        s0 = 0.f; s1 = 0.f;
        racc(a3, k00,k01,k02, s0,s1);
        racc(a2, k10,k11,k12, s0,s1);
        racc(a1, k20,k21,k22, s0,s1);
        const int y2 = yu - 3;
        const bool act2 = (y2 >= ytop - 1) && (y2 <= ytop + R) && ((unsigned)y2 < HH);
        const float bn0 = act2 ? fmaf(tau1, fh2.x - s0, a2.b) : 0.f;
        const float bn1 = act2 ? fmaf(tau1, fh2.y - s1, a2.c) : 0.f;

        // x3 row y3 = yu-5  (uses f row yu-5 = fh4) -> global store
        s0 = 0.f; s1 = 0.f;
        racc(b3, k00,k01,k02, s0,s1);
        racc(b2, k10,k11,k12, s0,s1);
        racc(b1, k20,k21,k22, s0,s1);
        const int y3 = yu - 5;
        if (y3 >= ytop && y3 < ytop + R) {
            const float o0 = fmaf(tau2, fh4.x - s0, b2.b);
            const float o1 = fmaf(tau2, fh4.y - s1, b2.c);
            *reinterpret_cast<float2*>(op + (size_t)y3 * WW + c2) = make_float2(o0, o1);
        }

        *reinterpret_cast<float2*>(&r1[wpar][2 + c2]) = make_float2(an0, an1);
        *reinterpret_cast<float2*>(&r2[wpar][2 + c2]) = make_float2(bn0, bn1);
        if (t == 0)   { r1[wpar][1] = 0.f;   r2[wpar][1] = 0.f; }
        if (t == 255) { r1[wpar][514] = 0.f; r2[wpar][514] = 0.f; }
        __syncthreads();

        u2 = u1; u1 = u0; u0 = un;
        a3 = a2; a2 = a1; aown0 = an0; aown1 = an1;
        b3 = b2; b2 = b1; bown0 = bn0; bown1 = bn1;
        fh4 = fh3; fh3 = fh2; fh2 = fh1; fh1 = fh0; fh0 = fn;
    }
}

extern "C" void kernel_launch(void* const* d_in, const int* in_sizes, int n_in,
                              void* d_out, int out_size, void* d_ws, size_t ws_size,
                              hipStream_t stream)
{
    const float* x_in = (const float*)d_in[0];
    const float* f_in = (const float*)d_in[1];
    const float* k_in = (const float*)d_in[2];
    const float* u_in = (const float*)d_in[3];
    float* out = (float*)d_out;

    float* bufA = (float*)d_ws;                       // 64 MB ping-pong field
    float* pmW0 = bufA + (size_t)BB * PLANE;          // [BB*NSTRIPE]
    float* pmW1 = pmW0 + BB * NSTRIPE;
    float* pmZ  = pmW1 + BB * NSTRIPE;
    float* taus = pmZ  + BB * NSTRIPE;                // [15*BB]

    dim3 blk(256), grd(NSTRIPE, BB);

    // ---- 10 fused power passes (2 conv levels each = 20 iterations) ----
    const float* src = u_in;
    for (int g = 0; g < 10; ++g) {
        float* dst = (g == 9) ? nullptr : ((g & 1) ? out : bufA);
        const float* pprev = g ? ((g & 1) ? pmW0 : pmW1) : nullptr;
        float* pw = (g & 1) ? pmW1 : pmW0;
        conv_fused<<<grd, blk, 0, stream>>>(src, k_in, pprev, dst, pw, pmZ);
        if (dst) src = dst;
    }

    // last pass (g=9) wrote pmW1 (level-20 maxima) and pmZ (level-19 maxima)
    tau_fused<<<BB, 64, 0, stream>>>(pmZ, pmW1, taus);

    // ---- 5 fused Chebyshev passes (3 steps each = 15); last lands in d_out ----
    const float* xs = x_in;
    for (int g = 0; g < 5; ++g) {
        float* dst = (g & 1) ? bufA : out;
        cheby_fused<<<grd, blk, 0, stream>>>(xs, f_in, k_in, taus + (size_t)(3 * g) * BB, dst);
        xs = dst;
    }
}

// Round 6
// 367.353 us; speedup vs baseline: 37.3778x; 1.5759x over previous
//
#include <hip/hip_runtime.h>

#define BB 64
#define HH 512
#define WW 512
#define PLANE (HH * WW)
#define R 32
#define NSTRIPE (HH / R)        // 16
#define N_CHEBY 15
#define FD 5                    // fusion depth (both phases)
#define STEPS (R + 3 * FD - 1)  // 46
#define LOADCUT (R + 2 * FD - 1) // 41: last row load at p=40

struct Sl { float a, b, c, d; };

__device__ __forceinline__ void racc(const Sl& s, float k0, float k1, float k2,
                                     float& o0, float& o1) {
    o0 = fmaf(k0, s.a, fmaf(k1, s.b, fmaf(k2, s.c, o0)));
    o1 = fmaf(k0, s.b, fmaf(k1, s.c, fmaf(k2, s.d, o1)));
}

__device__ __forceinline__ Sl ldsl(const float* pl, int row, int c2, bool ok) {
    Sl s = {0.f, 0.f, 0.f, 0.f};
    if (ok) {
        const float* rp = pl + (size_t)row * WW;
        float2 v = *reinterpret_cast<const float2*>(rp + c2);
        s.b = v.x; s.c = v.y;
        if (c2 > 0)      s.a = rp[c2 - 1];
        if (c2 + 2 < WW) s.d = rp[c2 + 2];
    }
    return s;
}

// Barrier WITHOUT vmcnt drain: flush LDS writes, but leave global prefetch
// loads in flight (compiler inserts precise vmcnt(N) at their register use).
__device__ __forceinline__ void softbar() {
    __asm__ volatile("s_waitcnt lgkmcnt(0)" ::: "memory");
    __builtin_amdgcn_s_barrier();
}

// ---------------------------------------------------------------------------
// Fused 5-level power pass: v1 = inv*A(in), v_{j+1} = A(v_j), j=1..4.
// Tracks mz = max|v4|, mw = max|v5| (per stripe). out==null on last pass.
// Row pipeline: level j's row lags input row yu by 2j-1. 4 LDS rings carry
// each intermediate level's row to the +1 step for neighbor-column exchange.
// ---------------------------------------------------------------------------
__global__ __launch_bounds__(256, 4) void conv_fused5(
    const float* __restrict__ in, const float* __restrict__ kern,
    const float* __restrict__ pm_prev, float* __restrict__ out,
    float* __restrict__ pmw, float* __restrict__ pmz)
{
    const int b = blockIdx.y, stripe = blockIdx.x, ytop = stripe * R;
    const int t = threadIdx.x, c2 = t << 1;

    __shared__ float re[FD - 1][2][258], ro[FD - 1][2][258];
    __shared__ float sred[8];
    __shared__ float sinv;

    // guard cells (written once; reads use [0] left-guard, [257] right-guard)
    if (t < 2 * (FD - 1)) {
        const int l = t >> 1, par = t & 1;
        re[l][par][0] = 0.f; re[l][par][257] = 0.f;
        ro[l][par][0] = 0.f; ro[l][par][257] = 0.f;
    }
    if (pm_prev && t < 64) {
        float v = (t < NSTRIPE) ? pm_prev[b * NSTRIPE + t] : 0.f;
#pragma unroll
        for (int o = 8; o; o >>= 1) v = fmaxf(v, __shfl_xor(v, o, 64));
        if (t == 0) sinv = 1.f / v;
    }
    __syncthreads();
    const float invv = pm_prev ? sinv : 1.f;

    const float* kb = kern + b * 9;
    const float k00=kb[0],k01=kb[1],k02=kb[2],k10=kb[3],k11=kb[4],k12=kb[5],
                k20=kb[6],k21=kb[7],k22=kb[8];
    const float* ip = in + (size_t)b * PLANE;
    float* op = out ? out + (size_t)b * PLANE : nullptr;

    Sl u2 = {0,0,0,0}, u1 = {0,0,0,0};
    Sl ltp[FD - 1], lmd[FD - 1];
    float own0[FD - 1], own1[FD - 1];
#pragma unroll
    for (int l = 0; l < FD - 1; ++l) {
        ltp[l] = Sl{0,0,0,0}; lmd[l] = Sl{0,0,0,0};
        own0[l] = 0.f; own1[l] = 0.f;
    }
    float mz = 0.f, mw = 0.f;
    Sl u0 = ldsl(ip, ytop - FD, c2, (unsigned)(ytop - FD) < HH);

#pragma unroll 2
    for (int p = 0; p < STEPS; ++p) {
        const int yu = ytop - FD + p;
        Sl un = ldsl(ip, yu + 1, c2, ((unsigned)(yu + 1) < HH) && (p < LOADCUT));

        const int rpar = (p + 1) & 1, wpar = p & 1;
        Sl am[FD - 1];
#pragma unroll
        for (int l = 0; l < FD - 1; ++l) {
            am[l].a = ro[l][rpar][t];
            am[l].b = own0[l];
            am[l].c = own1[l];
            am[l].d = re[l][rpar][2 + t];
        }

        float v0[FD], v1[FD];
        {   // level 1 (normalized)
            float s0 = 0.f, s1 = 0.f;
            racc(u2, k00,k01,k02, s0,s1);
            racc(u1, k10,k11,k12, s0,s1);
            racc(u0, k20,k21,k22, s0,s1);
            const int y = yu - 1;
            const bool act = (y >= ytop - (FD-1)) && (y <= ytop + R + FD - 2)
                          && ((unsigned)y < HH);
            v0[0] = act ? s0 * invv : 0.f;
            v1[0] = act ? s1 * invv : 0.f;
        }
#pragma unroll
        for (int j = 2; j <= FD; ++j) {
            float s0 = 0.f, s1 = 0.f;
            racc(ltp[j-2], k00,k01,k02, s0,s1);
            racc(lmd[j-2], k10,k11,k12, s0,s1);
            racc(am[j-2],  k20,k21,k22, s0,s1);
            const int y = yu - (2*j - 1);
            if (j < FD) {
                const bool act = (y >= ytop - (FD-j)) && (y <= ytop + R + FD - j - 1)
                              && ((unsigned)y < HH);
                v0[j-1] = act ? s0 : 0.f;
                v1[j-1] = act ? s1 : 0.f;
                if (j == FD - 1)
                    mz = fmaxf(mz, fmaxf(fabsf(v0[j-1]), fabsf(v1[j-1])));
            } else {
                if (y >= ytop && y < ytop + R) {
                    mw = fmaxf(mw, fmaxf(fabsf(s0), fabsf(s1)));
                    if (op)
                        *reinterpret_cast<float2*>(op + (size_t)y * WW + c2) =
                            make_float2(s0, s1);
                }
            }
        }
#pragma unroll
        for (int l = 0; l < FD - 1; ++l) {
            re[l][wpar][1 + t] = v0[l];
            ro[l][wpar][1 + t] = v1[l];
            ltp[l] = lmd[l]; lmd[l] = am[l];
            own0[l] = v0[l]; own1[l] = v1[l];
        }
        u2 = u1; u1 = u0; u0 = un;
        softbar();
    }

#pragma unroll
    for (int o = 32; o; o >>= 1) {
        mz = fmaxf(mz, __shfl_xor(mz, o, 64));
        mw = fmaxf(mw, __shfl_xor(mw, o, 64));
    }
    if ((t & 63) == 0) { sred[t >> 6] = mz; sred[4 + (t >> 6)] = mw; }
    __syncthreads();
    if (t == 0) {
        pmz[b * NSTRIPE + stripe] =
            fmaxf(fmaxf(sred[0], sred[1]), fmaxf(sred[2], sred[3]));
        pmw[b * NSTRIPE + stripe] =
            fmaxf(fmaxf(sred[4], sred[5]), fmaxf(sred[6], sred[7]));
    }
}

// ---------------------------------------------------------------------------
// m = max|v5| / max|v4| of final power pass; taus[it*BB+b], it=0..14.
// ---------------------------------------------------------------------------
__global__ __launch_bounds__(64) void tau_fused(
    const float* __restrict__ pmz, const float* __restrict__ pmw,
    float* __restrict__ taus)
{
    const int b = blockIdx.x, t = threadIdx.x;
    float vz = (t < NSTRIPE) ? pmz[b * NSTRIPE + t] : 0.f;
    float vw = (t < NSTRIPE) ? pmw[b * NSTRIPE + t] : 0.f;
#pragma unroll
    for (int o = 8; o; o >>= 1) {
        vz = fmaxf(vz, __shfl_xor(vz, o, 64));
        vw = fmaxf(vw, __shfl_xor(vw, o, 64));
    }
    if (t < N_CHEBY) {
        const float m = vw / vz;
        const double rr = cos(M_PI * (2.0 * t + 1.0) / (2.0 * N_CHEBY));
        const float denom = m + m / 3.0f - (m / 3.0f - m) * (float)rr;
        taus[t * BB + b] = 2.0f / denom;
    }
}

// ---------------------------------------------------------------------------
// Fused 5-level Chebyshev pass: x_j = x_{j-1} + tau_{j-1}*(f - A x_{j-1}).
// f carried in a 9-deep register ring (level j uses fh[2(j-1)]).
// ---------------------------------------------------------------------------
__global__ __launch_bounds__(256, 4) void cheby_fused5(
    const float* __restrict__ xin, const float* __restrict__ fin,
    const float* __restrict__ kern, const float* __restrict__ tau5,
    float* __restrict__ xout)
{
    const int b = blockIdx.y, stripe = blockIdx.x, ytop = stripe * R;
    const int t = threadIdx.x, c2 = t << 1;

    __shared__ float re[FD - 1][2][258], ro[FD - 1][2][258];

    if (t < 2 * (FD - 1)) {
        const int l = t >> 1, par = t & 1;
        re[l][par][0] = 0.f; re[l][par][257] = 0.f;
        ro[l][par][0] = 0.f; ro[l][par][257] = 0.f;
    }
    __syncthreads();

    const float* kb = kern + b * 9;
    const float k00=kb[0],k01=kb[1],k02=kb[2],k10=kb[3],k11=kb[4],k12=kb[5],
                k20=kb[6],k21=kb[7],k22=kb[8];
    float tau[FD];
#pragma unroll
    for (int j = 0; j < FD; ++j) tau[j] = tau5[j * BB + b];

    const float* xp = xin + (size_t)b * PLANE;
    const float* fp = fin + (size_t)b * PLANE;
    float* op = xout + (size_t)b * PLANE;

    Sl u2 = {0,0,0,0}, u1 = {0,0,0,0};
    Sl ltp[FD - 1], lmd[FD - 1];
    float own0[FD - 1], own1[FD - 1];
#pragma unroll
    for (int l = 0; l < FD - 1; ++l) {
        ltp[l] = Sl{0,0,0,0}; lmd[l] = Sl{0,0,0,0};
        own0[l] = 0.f; own1[l] = 0.f;
    }
    float2 fh[2 * FD - 1];
#pragma unroll
    for (int k = 1; k < 2 * FD - 1; ++k) fh[k] = make_float2(0.f, 0.f);

    Sl u0 = ldsl(xp, ytop - FD, c2, (unsigned)(ytop - FD) < HH);
    {
        const int yf = ytop - FD - 1;
        fh[0] = ((unsigned)yf < HH)
            ? *reinterpret_cast<const float2*>(fp + (size_t)yf * WW + c2)
            : make_float2(0.f, 0.f);
    }

#pragma unroll 2
    for (int p = 0; p < STEPS; ++p) {
        const int yu = ytop - FD + p;
        const bool ldok = (p < LOADCUT);
        Sl un = ldsl(xp, yu + 1, c2, ((unsigned)(yu + 1) < HH) && ldok);
        const float2 fn = (((unsigned)yu < HH) && ldok)
            ? *reinterpret_cast<const float2*>(fp + (size_t)yu * WW + c2)
            : make_float2(0.f, 0.f);

        const int rpar = (p + 1) & 1, wpar = p & 1;
        Sl am[FD - 1];
#pragma unroll
        for (int l = 0; l < FD - 1; ++l) {
            am[l].a = ro[l][rpar][t];
            am[l].b = own0[l];
            am[l].c = own1[l];
            am[l].d = re[l][rpar][2 + t];
        }

        float v0[FD], v1[FD];
        {   // level 1: x1 = x + tau0*(f - A x)   at row yu-1
            float s0 = 0.f, s1 = 0.f;
            racc(u2, k00,k01,k02, s0,s1);
            racc(u1, k10,k11,k12, s0,s1);
            racc(u0, k20,k21,k22, s0,s1);
            const int y = yu - 1;
            const bool act = (y >= ytop - (FD-1)) && (y <= ytop + R + FD - 2)
                          && ((unsigned)y < HH);
            v0[0] = act ? fmaf(tau[0], fh[0].x - s0, u1.b) : 0.f;
            v1[0] = act ? fmaf(tau[0], fh[0].y - s1, u1.c) : 0.f;
        }
#pragma unroll
        for (int j = 2; j <= FD; ++j) {
            float s0 = 0.f, s1 = 0.f;
            racc(ltp[j-2], k00,k01,k02, s0,s1);
            racc(lmd[j-2], k10,k11,k12, s0,s1);
            racc(am[j-2],  k20,k21,k22, s0,s1);
            const int y = yu - (2*j - 1);
            const float2 fv = fh[2*(j-1)];
            if (j < FD) {
                const bool act = (y >= ytop - (FD-j)) && (y <= ytop + R + FD - j - 1)
                              && ((unsigned)y < HH);
                v0[j-1] = act ? fmaf(tau[j-1], fv.x - s0, lmd[j-2].b) : 0.f;
                v1[j-1] = act ? fmaf(tau[j-1], fv.y - s1, lmd[j-2].c) : 0.f;
            } else {
                if (y >= ytop && y < ytop + R) {
                    const float o0 = fmaf(tau[FD-1], fv.x - s0, lmd[j-2].b);
                    const float o1 = fmaf(tau[FD-1], fv.y - s1, lmd[j-2].c);
                    *reinterpret_cast<float2*>(op + (size_t)y * WW + c2) =
                        make_float2(o0, o1);
                }
            }
        }
#pragma unroll
        for (int l = 0; l < FD - 1; ++l) {
            re[l][wpar][1 + t] = v0[l];
            ro[l][wpar][1 + t] = v1[l];
            ltp[l] = lmd[l]; lmd[l] = am[l];
            own0[l] = v0[l]; own1[l] = v1[l];
        }
        u2 = u1; u1 = u0; u0 = un;
#pragma unroll
        for (int k = 2 * FD - 2; k > 0; --k) fh[k] = fh[k - 1];
        fh[0] = fn;
        softbar();
    }
}

extern "C" void kernel_launch(void* const* d_in, const int* in_sizes, int n_in,
                              void* d_out, int out_size, void* d_ws, size_t ws_size,
                              hipStream_t stream)
{
    const float* x_in = (const float*)d_in[0];
    const float* f_in = (const float*)d_in[1];
    const float* k_in = (const float*)d_in[2];
    const float* u_in = (const float*)d_in[3];
    float* out = (float*)d_out;

    float* bufA = (float*)d_ws;                 // 64 MB ping-pong field
    float* pmW0 = bufA + (size_t)BB * PLANE;
    float* pmW1 = pmW0 + BB * NSTRIPE;
    float* pmZ  = pmW1 + BB * NSTRIPE;
    float* taus = pmZ  + BB * NSTRIPE;          // [15*BB]

    dim3 blk(256), grd(NSTRIPE, BB);

    // ---- 4 fused power passes (5 levels each = 20 iterations) ----
    // u_in -> bufA -> out -> bufA -> (none)
    const float* src = u_in;
    for (int g = 0; g < 4; ++g) {
        float* dst = (g == 3) ? nullptr : ((g & 1) ? out : bufA);
        const float* pprev = g ? ((g & 1) ? pmW0 : pmW1) : nullptr;
        float* pw = (g & 1) ? pmW1 : pmW0;
        conv_fused5<<<grd, blk, 0, stream>>>(src, k_in, pprev, dst, pw, pmZ);
        if (dst) src = dst;
    }

    // final pass (g=3) wrote pmW1 (level-20 maxima) and pmZ (level-19 maxima)
    tau_fused<<<BB, 64, 0, stream>>>(pmZ, pmW1, taus);

    // ---- 3 fused Chebyshev passes (5 steps each = 15) ----
    // x_in -> out -> bufA -> out   (src != dst every pass)
    cheby_fused5<<<grd, blk, 0, stream>>>(x_in, f_in, k_in, taus + 0 * BB, out);
    cheby_fused5<<<grd, blk, 0, stream>>>(out,  f_in, k_in, taus + 5 * BB, bufA);
    cheby_fused5<<<grd, blk, 0, stream>>>(bufA, f_in, k_in, taus + 10 * BB, out);
}